// Round 1
// baseline (186.033 us; speedup 1.0000x reference)
//
#include <hip/hip_runtime.h>
#include <hip/hip_bf16.h>

typedef float f32x4 __attribute__((ext_vector_type(4)));
typedef __bf16 bf16x8 __attribute__((ext_vector_type(8)));
typedef unsigned short u16x8 __attribute__((ext_vector_type(8)));
typedef unsigned short u16x4 __attribute__((ext_vector_type(4)));
typedef int i32x4 __attribute__((ext_vector_type(4)));

#define NEG_BIG_F (-1000000000.0f)

__device__ __forceinline__ unsigned short f2bf(float f) {
  unsigned int u = __float_as_uint(f);
  u += 0x7FFFu + ((u >> 16) & 1u);   // round-to-nearest-even
  return (unsigned short)(u >> 16);
}

__device__ __forceinline__ u16x8 cvt8(f32x4 a, f32x4 b) {
  u16x8 r;
  r[0] = f2bf(a[0]); r[1] = f2bf(a[1]); r[2] = f2bf(a[2]); r[3] = f2bf(a[3]);
  r[4] = f2bf(b[0]); r[5] = f2bf(b[1]); r[6] = f2bf(b[2]); r[7] = f2bf(b[3]);
  return r;
}

// ---------------------------------------------------------------------------
// proj_gemm: Y[m][n] = sum_k X[m][k] * W[n][k]   (fp32 in, bf16 out)
// X: M x 512 fp32 (M = 16384), W: 512 x 512 fp32 (row = output feature).
// TRANS: write Y as vt[b][n][s] (b = m>>10, s = m&1023) for the attn@v GEMM.
// grid (M/128, 512/128), block 256 (4 waves), 128x128 tile, BK=32.
// ---------------------------------------------------------------------------
template <bool TRANS>
__global__ __launch_bounds__(256) void proj_gemm(
    const float* __restrict__ X, const float* __restrict__ W,
    unsigned short* __restrict__ Y)
{
  const int K = 512;
  __shared__ __align__(16) unsigned short As[128][40];
  __shared__ __align__(16) unsigned short Bs[128][40];

  const int tid = threadIdx.x;
  const int sr = tid >> 1;            // staging row 0..127
  const int sc = (tid & 1) * 16;      // staging col 0 / 16
  const int m0 = blockIdx.x * 128, n0 = blockIdx.y * 128;
  const int lane = tid & 63, wave = tid >> 6;
  const int wr = (wave >> 1) * 64, wc = (wave & 1) * 64;
  const int fr = lane & 15, fq = lane >> 4;

  f32x4 acc[4][4] = {};

  const float* xa = X + (size_t)(m0 + sr) * K + sc;
  const float* wb = W + (size_t)(n0 + sr) * K + sc;

  for (int kt = 0; kt < K; kt += 32) {
    *(u16x8*)&As[sr][sc]     = cvt8(*(const f32x4*)(xa + kt),     *(const f32x4*)(xa + kt + 4));
    *(u16x8*)&As[sr][sc + 8] = cvt8(*(const f32x4*)(xa + kt + 8), *(const f32x4*)(xa + kt + 12));
    *(u16x8*)&Bs[sr][sc]     = cvt8(*(const f32x4*)(wb + kt),     *(const f32x4*)(wb + kt + 4));
    *(u16x8*)&Bs[sr][sc + 8] = cvt8(*(const f32x4*)(wb + kt + 8), *(const f32x4*)(wb + kt + 12));
    __syncthreads();
    bf16x8 af[4], bfr[4];
    #pragma unroll
    for (int t = 0; t < 4; t++) {
      af[t]  = *(const bf16x8*)&As[wr + t * 16 + fr][fq * 8];
      bfr[t] = *(const bf16x8*)&Bs[wc + t * 16 + fr][fq * 8];
    }
    #pragma unroll
    for (int mt = 0; mt < 4; mt++)
      #pragma unroll
      for (int nt = 0; nt < 4; nt++)
        acc[mt][nt] = __builtin_amdgcn_mfma_f32_16x16x32_bf16(af[mt], bfr[nt], acc[mt][nt], 0, 0, 0);
    __syncthreads();
  }

  #pragma unroll
  for (int mt = 0; mt < 4; mt++)
    #pragma unroll
    for (int nt = 0; nt < 4; nt++)
      #pragma unroll
      for (int r = 0; r < 4; r++) {
        const int m = m0 + wr + mt * 16 + fq * 4 + r;
        const int n = n0 + wc + nt * 16 + fr;
        const unsigned short h = f2bf(acc[mt][nt][r]);
        if (TRANS) {
          const int b = m >> 10, s = m & 1023;
          Y[((size_t)b * 512 + n) * 1024 + s] = h;
        } else {
          Y[(size_t)m * 512 + n] = h;
        }
      }
}

// ---------------------------------------------------------------------------
// bt_gemm: batched C[m][n] = scale * sum_k A[m][k] * B[n][k]  (bf16 in, f32 out)
// A: M x K (K-contiguous), B: N x K (K-contiguous). blockIdx.z = batch.
// grid (M/128, N/128, batches), block 256, 128x128 tile, BK=32.
// ---------------------------------------------------------------------------
__global__ __launch_bounds__(256) void bt_gemm(
    const unsigned short* __restrict__ A, const unsigned short* __restrict__ B,
    float* __restrict__ C, int N, int K,
    size_t strA, size_t strB, size_t strC, float scale)
{
  __shared__ __align__(16) unsigned short As[128][40];
  __shared__ __align__(16) unsigned short Bs[128][40];

  const unsigned short* Ab = A + strA * blockIdx.z;
  const unsigned short* Bb = B + strB * blockIdx.z;
  float* Cb = C + strC * blockIdx.z;

  const int tid = threadIdx.x;
  const int sr = tid >> 1;
  const int sc = (tid & 1) * 16;
  const int m0 = blockIdx.x * 128, n0 = blockIdx.y * 128;
  const int lane = tid & 63, wave = tid >> 6;
  const int wr = (wave >> 1) * 64, wc = (wave & 1) * 64;
  const int fr = lane & 15, fq = lane >> 4;

  f32x4 acc[4][4] = {};

  const unsigned short* xa = Ab + (size_t)(m0 + sr) * K + sc;
  const unsigned short* wb = Bb + (size_t)(n0 + sr) * K + sc;

  for (int kt = 0; kt < K; kt += 32) {
    *(u16x8*)&As[sr][sc]     = *(const u16x8*)(xa + kt);
    *(u16x8*)&As[sr][sc + 8] = *(const u16x8*)(xa + kt + 8);
    *(u16x8*)&Bs[sr][sc]     = *(const u16x8*)(wb + kt);
    *(u16x8*)&Bs[sr][sc + 8] = *(const u16x8*)(wb + kt + 8);
    __syncthreads();
    bf16x8 af[4], bfr[4];
    #pragma unroll
    for (int t = 0; t < 4; t++) {
      af[t]  = *(const bf16x8*)&As[wr + t * 16 + fr][fq * 8];
      bfr[t] = *(const bf16x8*)&Bs[wc + t * 16 + fr][fq * 8];
    }
    #pragma unroll
    for (int mt = 0; mt < 4; mt++)
      #pragma unroll
      for (int nt = 0; nt < 4; nt++)
        acc[mt][nt] = __builtin_amdgcn_mfma_f32_16x16x32_bf16(af[mt], bfr[nt], acc[mt][nt], 0, 0, 0);
    __syncthreads();
  }

  #pragma unroll
  for (int mt = 0; mt < 4; mt++)
    #pragma unroll
    for (int nt = 0; nt < 4; nt++)
      #pragma unroll
      for (int r = 0; r < 4; r++) {
        const int m = m0 + wr + mt * 16 + fq * 4 + r;
        const int n = n0 + wc + nt * 16 + fr;
        Cb[(size_t)m * N + n] = acc[mt][nt][r] * scale;
      }
}

// ---------------------------------------------------------------------------
// softmax_mask: one wave per row of 1024 scores (in-place fp32 in d_out attn
// region). softmax over full row, THEN mask (reference masks after softmax):
// attn = mask ? p : NEG_BIG. Also writes a bf16 copy for the attn@v GEMM.
// block 256 = 4 waves = 4 rows; grid = B*S/4.
// ---------------------------------------------------------------------------
__global__ __launch_bounds__(256) void softmax_mask(
    float* __restrict__ attn, unsigned short* __restrict__ attn16,
    const int* __restrict__ mask)
{
  const int lane = threadIdx.x & 63;
  const int wave = threadIdx.x >> 6;
  const int row = blockIdx.x * 4 + wave;   // 0 .. 16383
  const int b = row >> 10;

  float* rp = attn + (size_t)row * 1024;
  f32x4 v[4];
  float mx = -3.0e38f;
  #pragma unroll
  for (int i = 0; i < 4; i++) {
    v[i] = *(const f32x4*)(rp + i * 256 + lane * 4);
    mx = fmaxf(mx, fmaxf(fmaxf(v[i][0], v[i][1]), fmaxf(v[i][2], v[i][3])));
  }
  #pragma unroll
  for (int o = 32; o > 0; o >>= 1) mx = fmaxf(mx, __shfl_xor(mx, o));

  float sum = 0.f;
  #pragma unroll
  for (int i = 0; i < 4; i++) {
    v[i][0] = __expf(v[i][0] - mx);
    v[i][1] = __expf(v[i][1] - mx);
    v[i][2] = __expf(v[i][2] - mx);
    v[i][3] = __expf(v[i][3] - mx);
    sum += v[i][0] + v[i][1] + v[i][2] + v[i][3];
  }
  #pragma unroll
  for (int o = 32; o > 0; o >>= 1) sum += __shfl_xor(sum, o);
  const float inv = 1.0f / sum;

  const int* mrow = mask + b * 1024;
  unsigned short* hp = attn16 + (size_t)row * 1024;
  #pragma unroll
  for (int i = 0; i < 4; i++) {
    const i32x4 mv = *(const i32x4*)(mrow + i * 256 + lane * 4);
    f32x4 pv;
    pv[0] = mv[0] ? v[i][0] * inv : NEG_BIG_F;
    pv[1] = mv[1] ? v[i][1] * inv : NEG_BIG_F;
    pv[2] = mv[2] ? v[i][2] * inv : NEG_BIG_F;
    pv[3] = mv[3] ? v[i][3] * inv : NEG_BIG_F;
    *(f32x4*)(rp + i * 256 + lane * 4) = pv;
    u16x4 h;
    h[0] = f2bf(pv[0]); h[1] = f2bf(pv[1]); h[2] = f2bf(pv[2]); h[3] = f2bf(pv[3]);
    *(u16x4*)(hp + i * 256 + lane * 4) = h;
  }
}

// ---------------------------------------------------------------------------
extern "C" void kernel_launch(void* const* d_in, const int* in_sizes, int n_in,
                              void* d_out, int out_size, void* d_ws, size_t ws_size,
                              hipStream_t stream)
{
  const float* Q  = (const float*)d_in[0];
  const float* Kx = (const float*)d_in[1];
  const float* V  = (const float*)d_in[2];
  const float* WQ = (const float*)d_in[3];
  const float* WK = (const float*)d_in[4];
  const float* WV = (const float*)d_in[5];
  const int* mask = (const int*)d_in[6];

  const int B = 16, S = 1024, D = 512;
  float* out_f  = (float*)d_out;                        // B*S*D
  float* attn_f = out_f + (size_t)B * S * D;            // B*S*S

  // workspace layout (bf16 as ushort):
  //   qb [0, 16.78MB) | kb [16.78, 33.55) | vt [33.55, 50.33)  (vt = [b][e][s])
  //   attn16 aliases [0, 33.55) — qb/kb are dead once scores are computed.
  unsigned short* qb = (unsigned short*)d_ws;
  unsigned short* kb = qb + (size_t)B * S * D;
  unsigned short* vt = kb + (size_t)B * S * D;
  unsigned short* attn16 = (unsigned short*)d_ws;

  // 1) projections: q = Q @ WQ^T (bf16), k = K @ WK^T, vt = transpose(V @ WV^T)
  proj_gemm<false><<<dim3(128, 4, 1), 256, 0, stream>>>(Q,  WQ, qb);
  proj_gemm<false><<<dim3(128, 4, 1), 256, 0, stream>>>(Kx, WK, kb);
  proj_gemm<true ><<<dim3(128, 4, 1), 256, 0, stream>>>(V,  WV, vt);

  // 2) raw scores = q k^T / sqrt(512)  -> fp32 into attn region of d_out
  bt_gemm<<<dim3(8, 8, 16), 256, 0, stream>>>(
      qb, kb, attn_f, 1024, 512,
      (size_t)S * D, (size_t)S * D, (size_t)S * S, 0.044194173824159216f);

  // 3) softmax over k, then post-softmax mask; fp32 to d_out + bf16 to ws
  softmax_mask<<<dim3(B * S / 4), 256, 0, stream>>>(attn_f, attn16, mask);

  // 4) out = attn_masked @ v   (B operand = vt, K-contiguous)
  bt_gemm<<<dim3(8, 4, 16), 256, 0, stream>>>(
      attn16, vt, out_f, 512, 1024,
      (size_t)S * S, (size_t)D * S, (size_t)S * D, 1.0f);
}

// Round 2
// 180.477 us; speedup vs baseline: 1.0308x; 1.0308x over previous
//
#include <hip/hip_runtime.h>
#include <hip/hip_bf16.h>

typedef float f32x4 __attribute__((ext_vector_type(4)));
typedef __bf16 bf16x8 __attribute__((ext_vector_type(8)));
typedef unsigned short u16x8 __attribute__((ext_vector_type(8)));
typedef int i32x4 __attribute__((ext_vector_type(4)));

#define NEG_BIG_F (-1000000000.0f)

__device__ __forceinline__ unsigned short f2bf(float f) {
  unsigned int u = __float_as_uint(f);
  u += 0x7FFFu + ((u >> 16) & 1u);   // round-to-nearest-even
  return (unsigned short)(u >> 16);
}

__device__ __forceinline__ u16x8 cvt8(f32x4 a, f32x4 b) {
  u16x8 r;
  r[0] = f2bf(a[0]); r[1] = f2bf(a[1]); r[2] = f2bf(a[2]); r[3] = f2bf(a[3]);
  r[4] = f2bf(b[0]); r[5] = f2bf(b[1]); r[6] = f2bf(b[2]); r[7] = f2bf(b[3]);
  return r;
}

// async 16B global -> LDS (dest is wave-uniform base + lane*16; we pass the
// per-lane address whose lane-0 value is the base, consistent either way)
__device__ __forceinline__ void gload16(const unsigned short* g, void* l) {
  __builtin_amdgcn_global_load_lds(
      (const __attribute__((address_space(1))) unsigned int*)g,
      (__attribute__((address_space(3))) unsigned int*)l, 16, 0, 0);
}

// ---------------------------------------------------------------------------
// cvtW: convert the three 512x512 fp32 weight matrices to bf16 (z picks W).
// ---------------------------------------------------------------------------
__global__ __launch_bounds__(256) void cvtW(
    const float* __restrict__ w0, const float* __restrict__ w1,
    const float* __restrict__ w2, unsigned short* __restrict__ out)
{
  const float* src = blockIdx.z == 0 ? w0 : (blockIdx.z == 1 ? w1 : w2);
  unsigned short* dst = out + (size_t)blockIdx.z * 262144;
  const int i = (blockIdx.x * 256 + threadIdx.x) * 8;   // grid.x=128 covers 512*512
  f32x4 a = *(const f32x4*)(src + i);
  f32x4 b = *(const f32x4*)(src + i + 4);
  *(u16x8*)&dst[i] = cvt8(a, b);
}

// ---------------------------------------------------------------------------
// gemm128: C[m][n] = scale * sum_k A[m][k] * B[n][k], 128x128 tile, BK=32.
//   A: f32 (AF32=1, reg-stage + convert) or bf16 (AF32=0, global_load_lds).
//   B: always bf16, K-contiguous, staged via global_load_lds (linear LDS).
//   OMODE 0: f32 * scale -> C[m][n]         (batched via blockIdx.z)
//   OMODE 1: bf16 -> C[m][n]
//   OMODE 2: bf16 -> C[((m>>10)*512 + n)*1024 + (m&1023)]   (vt layout)
// grid (M/128, N/128, batches), block 256 (4 waves).
// ---------------------------------------------------------------------------
template <int AF32, int OMODE>
__global__ __launch_bounds__(256) void gemm128(
    const void* __restrict__ Ap, const unsigned short* __restrict__ Bp,
    void* __restrict__ Cp, int N, int K,
    size_t strA, size_t strB, size_t strC, float scale)
{
  constexpr int LDA = AF32 ? 40 : 32;   // pad the reg-staged side only
  __shared__ __align__(16) unsigned short As[128][LDA];
  __shared__ __align__(16) unsigned short Bs[128][32];

  const int tid = threadIdx.x;
  const int z = blockIdx.z;
  const int m0 = blockIdx.x * 128, n0 = blockIdx.y * 128;
  const int lane = tid & 63, wave = tid >> 6;
  const int wr = (wave >> 1) * 64, wc = (wave & 1) * 64;
  const int fr = lane & 15, fq = lane >> 4;

  f32x4 acc[4][4] = {};

  // B staging: chunk idx = r*256 + tid, r in {0,1}; row = idx>>2, col8 = (idx&3)*8
  const unsigned short* gB0 =
      Bp + strB * z + (size_t)(n0 + (tid >> 2)) * K + (tid & 3) * 8;
  const unsigned short* gB1 = gB0 + (size_t)64 * K;
  char* lB0 = (char*)&Bs[0][0] + tid * 16;
  char* lB1 = lB0 + 4096;

  // A staging
  const float* xa = nullptr;
  const unsigned short* gA0 = nullptr;
  const unsigned short* gA1 = nullptr;
  char* lA0 = (char*)&As[0][0] + tid * 16;
  char* lA1 = lA0 + 4096;
  if constexpr (AF32) {
    xa = (const float*)Ap + strA * z + (size_t)(m0 + (tid >> 1)) * K + (tid & 1) * 16;
  } else {
    gA0 = (const unsigned short*)Ap + strA * z + (size_t)(m0 + (tid >> 2)) * K + (tid & 3) * 8;
    gA1 = gA0 + (size_t)64 * K;
  }

  for (int kt = 0; kt < K; kt += 32) {
    if constexpr (AF32) {
      f32x4 a0 = *(const f32x4*)(xa + kt);
      f32x4 a1 = *(const f32x4*)(xa + kt + 4);
      f32x4 a2 = *(const f32x4*)(xa + kt + 8);
      f32x4 a3 = *(const f32x4*)(xa + kt + 12);
      *(u16x8*)&As[tid >> 1][(tid & 1) * 16]     = cvt8(a0, a1);
      *(u16x8*)&As[tid >> 1][(tid & 1) * 16 + 8] = cvt8(a2, a3);
    } else {
      gload16(gA0 + kt, lA0);
      gload16(gA1 + kt, lA1);
    }
    gload16(gB0 + kt, lB0);
    gload16(gB1 + kt, lB1);
    __syncthreads();

    bf16x8 af[4], bv[4];
    #pragma unroll
    for (int t = 0; t < 4; t++) {
      af[t] = *(const bf16x8*)&As[wr + t * 16 + fr][fq * 8];
      bv[t] = *(const bf16x8*)&Bs[wc + t * 16 + fr][fq * 8];
    }
    #pragma unroll
    for (int mt = 0; mt < 4; mt++)
      #pragma unroll
      for (int nt = 0; nt < 4; nt++)
        acc[mt][nt] = __builtin_amdgcn_mfma_f32_16x16x32_bf16(af[mt], bv[nt], acc[mt][nt], 0, 0, 0);
    __syncthreads();
  }

  #pragma unroll
  for (int mt = 0; mt < 4; mt++)
    #pragma unroll
    for (int nt = 0; nt < 4; nt++)
      #pragma unroll
      for (int r = 0; r < 4; r++) {
        const int m = m0 + wr + mt * 16 + fq * 4 + r;
        const int n = n0 + wc + nt * 16 + fr;
        if constexpr (OMODE == 0) {
          ((float*)Cp + strC * z)[(size_t)m * N + n] = acc[mt][nt][r] * scale;
        } else if constexpr (OMODE == 1) {
          ((unsigned short*)Cp)[(size_t)m * N + n] = f2bf(acc[mt][nt][r]);
        } else {
          const int b = m >> 10, s = m & 1023;
          ((unsigned short*)Cp)[((size_t)b * 512 + n) * 1024 + s] = f2bf(acc[mt][nt][r]);
        }
      }
}

// ---------------------------------------------------------------------------
// softmax_mask: one wave per row of 1024 fp32 scores, in place.
// softmax over the full row, THEN post-softmax mask (reference semantics):
// attn = mask ? p : NEG_BIG.
// ---------------------------------------------------------------------------
__global__ __launch_bounds__(256) void softmax_mask(
    float* __restrict__ attn, const int* __restrict__ mask)
{
  const int lane = threadIdx.x & 63;
  const int wave = threadIdx.x >> 6;
  const int row = blockIdx.x * 4 + wave;   // 0 .. 16383
  const int b = row >> 10;

  float* rp = attn + (size_t)row * 1024;
  f32x4 v[4];
  float mx = -3.0e38f;
  #pragma unroll
  for (int i = 0; i < 4; i++) {
    v[i] = *(const f32x4*)(rp + i * 256 + lane * 4);
    mx = fmaxf(mx, fmaxf(fmaxf(v[i][0], v[i][1]), fmaxf(v[i][2], v[i][3])));
  }
  #pragma unroll
  for (int o = 32; o > 0; o >>= 1) mx = fmaxf(mx, __shfl_xor(mx, o));

  float sum = 0.f;
  #pragma unroll
  for (int i = 0; i < 4; i++) {
    v[i][0] = __expf(v[i][0] - mx);
    v[i][1] = __expf(v[i][1] - mx);
    v[i][2] = __expf(v[i][2] - mx);
    v[i][3] = __expf(v[i][3] - mx);
    sum += v[i][0] + v[i][1] + v[i][2] + v[i][3];
  }
  #pragma unroll
  for (int o = 32; o > 0; o >>= 1) sum += __shfl_xor(sum, o);
  const float inv = 1.0f / sum;

  const int* mrow = mask + b * 1024;
  #pragma unroll
  for (int i = 0; i < 4; i++) {
    const i32x4 mv = *(const i32x4*)(mrow + i * 256 + lane * 4);
    f32x4 pv;
    pv[0] = mv[0] ? v[i][0] * inv : NEG_BIG_F;
    pv[1] = mv[1] ? v[i][1] * inv : NEG_BIG_F;
    pv[2] = mv[2] ? v[i][2] * inv : NEG_BIG_F;
    pv[3] = mv[3] ? v[i][3] * inv : NEG_BIG_F;
    *(f32x4*)(rp + i * 256 + lane * 4) = pv;
  }
}

// ---------------------------------------------------------------------------
extern "C" void kernel_launch(void* const* d_in, const int* in_sizes, int n_in,
                              void* d_out, int out_size, void* d_ws, size_t ws_size,
                              hipStream_t stream)
{
  const float* Q  = (const float*)d_in[0];
  const float* Kx = (const float*)d_in[1];
  const float* V  = (const float*)d_in[2];
  const float* WQ = (const float*)d_in[3];
  const float* WK = (const float*)d_in[4];
  const float* WV = (const float*)d_in[5];
  const int* mask = (const int*)d_in[6];

  const int B = 16, S = 1024, D = 512;
  float* out_f  = (float*)d_out;                 // B*S*D fp32
  float* attn_f = out_f + (size_t)B * S * D;     // B*S*S fp32 (raw scores -> attn)

  // ws (bf16 as ushort): qb | kb | vt | wb  (3*8.39M + 0.79M ushorts = 51.9 MB)
  unsigned short* qb = (unsigned short*)d_ws;
  unsigned short* kb = qb + (size_t)B * S * D;
  unsigned short* vt = kb + (size_t)B * S * D;
  unsigned short* wb = vt + (size_t)B * S * D;   // WQ16 | WK16 | WV16

  // 0) weights -> bf16
  cvtW<<<dim3(128, 1, 3), 256, 0, stream>>>(WQ, WK, WV, wb);

  // 1) projections (A = fp32 activations, B = bf16 weights)
  gemm128<1, 1><<<dim3(128, 4, 1), 256, 0, stream>>>(Q,  wb,          qb, 512, 512, 0, 0, 0, 1.f);
  gemm128<1, 1><<<dim3(128, 4, 1), 256, 0, stream>>>(Kx, wb + 262144, kb, 512, 512, 0, 0, 0, 1.f);
  gemm128<1, 2><<<dim3(128, 4, 1), 256, 0, stream>>>(V,  wb + 524288, vt, 512, 512, 0, 0, 0, 1.f);

  // 2) raw scores = q k^T / sqrt(512) -> fp32 attn region of d_out
  gemm128<0, 0><<<dim3(8, 8, 16), 256, 0, stream>>>(
      qb, kb, attn_f, 1024, 512,
      (size_t)S * D, (size_t)S * D, (size_t)S * S, 0.044194173824159216f);

  // 3) softmax + post-softmax mask, in place (fp32)
  softmax_mask<<<dim3(B * S / 4), 256, 0, stream>>>(attn_f, mask);

  // 4) out = attn_masked @ v  (A = fp32 attn, convert-on-stage; B = vt bf16)
  gemm128<1, 0><<<dim3(8, 4, 16), 256, 0, stream>>>(
      attn_f, vt, out_f, 512, 1024,
      (size_t)S * S, (size_t)D * S, (size_t)S * D, 1.f);
}

// Round 3
// 171.739 us; speedup vs baseline: 1.0832x; 1.0509x over previous
//
#include <hip/hip_runtime.h>
#include <hip/hip_bf16.h>

typedef float f32x4 __attribute__((ext_vector_type(4)));
typedef __bf16 bf16x8 __attribute__((ext_vector_type(8)));
typedef unsigned short u16x8 __attribute__((ext_vector_type(8)));
typedef unsigned short u16x4 __attribute__((ext_vector_type(4)));
typedef int i32x4 __attribute__((ext_vector_type(4)));

#define NEG_BIG_F (-1000000000.0f)
#define SCALE_F 0.044194173824159216f

__device__ __forceinline__ unsigned short f2bf(float f) {
  unsigned int u = __float_as_uint(f);
  u += 0x7FFFu + ((u >> 16) & 1u);   // round-to-nearest-even
  return (unsigned short)(u >> 16);
}

__device__ __forceinline__ u16x8 cvt8(f32x4 a, f32x4 b) {
  u16x8 r;
  r[0] = f2bf(a[0]); r[1] = f2bf(a[1]); r[2] = f2bf(a[2]); r[3] = f2bf(a[3]);
  r[4] = f2bf(b[0]); r[5] = f2bf(b[1]); r[6] = f2bf(b[2]); r[7] = f2bf(b[3]);
  return r;
}

__device__ __forceinline__ void gload16(const unsigned short* g, char* l) {
  __builtin_amdgcn_global_load_lds(
      (const __attribute__((address_space(1))) unsigned int*)g,
      (__attribute__((address_space(3))) unsigned int*)l, 16, 0, 0);
}

// ---------------------------------------------------------------------------
// cvtW: three 512x512 fp32 weight matrices -> bf16
// ---------------------------------------------------------------------------
__global__ __launch_bounds__(256) void cvtW(
    const float* __restrict__ w0, const float* __restrict__ w1,
    const float* __restrict__ w2, unsigned short* __restrict__ out)
{
  const float* src = blockIdx.z == 0 ? w0 : (blockIdx.z == 1 ? w1 : w2);
  unsigned short* dst = out + (size_t)blockIdx.z * 262144;
  const int i = (blockIdx.x * 256 + threadIdx.x) * 8;
  f32x4 a = *(const f32x4*)(src + i);
  f32x4 b = *(const f32x4*)(src + i + 4);
  *(u16x8*)&dst[i] = cvt8(a, b);
}

// ---------------------------------------------------------------------------
// proj3: all three projections in one dispatch (z = 0:Q 1:K 2:V).
// Y[m][n] = sum_k X[m][k] * W[n][k]. 128x128 tile, BK=32, 4 waves.
// 2-phase dbuf: STAGE(next) issued before compute(cur), ONE barrier/K-step.
// A: fp32 reg-staged (issue-early loads, write-late). B: bf16 gload_lds,
// both-sides swizzled (linear dest, inverse-swz source, swz read).
// z<2 -> Y[m][n] bf16; z==2 -> vt layout [(b*512+n)*1024+s].
// ---------------------------------------------------------------------------
__global__ __launch_bounds__(256) void proj3(
    const float* __restrict__ Q, const float* __restrict__ Kx,
    const float* __restrict__ V, const unsigned short* __restrict__ wb,
    unsigned short* __restrict__ qb, unsigned short* __restrict__ kb,
    unsigned short* __restrict__ vt)
{
  __shared__ __align__(16) unsigned short As[2][128][40];
  __shared__ __align__(16) unsigned short Bs[2][128][32];

  const int tid = threadIdx.x;
  const int z = blockIdx.z;
  const float* X = (z == 0) ? Q : (z == 1 ? Kx : V);
  const unsigned short* W = wb + (size_t)z * 262144;
  const int m0 = blockIdx.x * 128, n0 = blockIdx.y * 128;
  const int lane = tid & 63, wave = tid >> 6;
  const int wr = (wave >> 1) * 64, wc = (wave & 1) * 64;
  const int fr = lane & 15, fq = lane >> 4;

  f32x4 acc[4][4] = {};

  // A reg-stage: thread -> row tid>>1, 16 floats at col (tid&1)*16
  const int ar = tid >> 1, ac = (tid & 1) * 16;
  const float* xa = X + (size_t)(m0 + ar) * 512 + ac;

  // B gload chunks c0=tid, c1=256+tid: row=c>>2, source col8 inverse-swizzled
  const int c1 = 256 + tid;
  const int br0 = tid >> 2, br1 = c1 >> 2;
  const unsigned short* gB0 = W + (size_t)(n0 + br0) * 512 + ((tid & 3) ^ ((br0 >> 1) & 3)) * 8;
  const unsigned short* gB1 = W + (size_t)(n0 + br1) * 512 + ((c1 & 3) ^ ((br1 >> 1) & 3)) * 8;
  char* lB0 = (char*)&Bs[0][0][0] + tid * 16;
  char* lB1 = (char*)&Bs[0][0][0] + c1 * 16;

  // prologue: stage buffer 0 with kt=0
  {
    f32x4 a0 = *(const f32x4*)(xa),     a1 = *(const f32x4*)(xa + 4);
    f32x4 a2 = *(const f32x4*)(xa + 8), a3 = *(const f32x4*)(xa + 12);
    *(u16x8*)&As[0][ar][ac]     = cvt8(a0, a1);
    *(u16x8*)&As[0][ar][ac + 8] = cvt8(a2, a3);
    gload16(gB0, lB0);
    gload16(gB1, lB1);
  }
  __syncthreads();

  int cur = 0;
  for (int kt = 0; kt < 512 - 32; kt += 32) {
    const int nb = cur ^ 1;
    // issue next-tile A loads (global, to regs) + B gloads (async to LDS nb)
    f32x4 a0 = *(const f32x4*)(xa + kt + 32), a1 = *(const f32x4*)(xa + kt + 36);
    f32x4 a2 = *(const f32x4*)(xa + kt + 40), a3 = *(const f32x4*)(xa + kt + 44);
    gload16(gB0 + kt + 32, lB0 + nb * 8192);
    gload16(gB1 + kt + 32, lB1 + nb * 8192);
    // compute current
    bf16x8 af[4], bv[4];
    #pragma unroll
    for (int t = 0; t < 4; t++) {
      af[t] = *(const bf16x8*)&As[cur][wr + t * 16 + fr][fq * 8];
      const int brow = wc + t * 16 + fr;
      bv[t] = *(const bf16x8*)&Bs[cur][brow][(fq ^ ((brow >> 1) & 3)) * 8];
    }
    #pragma unroll
    for (int mt = 0; mt < 4; mt++)
      #pragma unroll
      for (int nt = 0; nt < 4; nt++)
        acc[mt][nt] = __builtin_amdgcn_mfma_f32_16x16x32_bf16(af[mt], bv[nt], acc[mt][nt], 0, 0, 0);
    // write-late A (waits on the f32 loads, lands in nb)
    *(u16x8*)&As[nb][ar][ac]     = cvt8(a0, a1);
    *(u16x8*)&As[nb][ar][ac + 8] = cvt8(a2, a3);
    __syncthreads();
    cur = nb;
  }
  // last tile
  {
    bf16x8 af[4], bv[4];
    #pragma unroll
    for (int t = 0; t < 4; t++) {
      af[t] = *(const bf16x8*)&As[cur][wr + t * 16 + fr][fq * 8];
      const int brow = wc + t * 16 + fr;
      bv[t] = *(const bf16x8*)&Bs[cur][brow][(fq ^ ((brow >> 1) & 3)) * 8];
    }
    #pragma unroll
    for (int mt = 0; mt < 4; mt++)
      #pragma unroll
      for (int nt = 0; nt < 4; nt++)
        acc[mt][nt] = __builtin_amdgcn_mfma_f32_16x16x32_bf16(af[mt], bv[nt], acc[mt][nt], 0, 0, 0);
  }

  // epilogue
  if (z == 2) {
    #pragma unroll
    for (int mt = 0; mt < 4; mt++)
      #pragma unroll
      for (int nt = 0; nt < 4; nt++)
        #pragma unroll
        for (int rr = 0; rr < 4; rr++) {
          const int m = m0 + wr + mt * 16 + fq * 4 + rr;
          const int n = n0 + wc + nt * 16 + fr;
          vt[((size_t)(m >> 10) * 512 + n) * 1024 + (m & 1023)] = f2bf(acc[mt][nt][rr]);
        }
  } else {
    unsigned short* Y = (z == 0) ? qb : kb;
    #pragma unroll
    for (int mt = 0; mt < 4; mt++)
      #pragma unroll
      for (int nt = 0; nt < 4; nt++)
        #pragma unroll
        for (int rr = 0; rr < 4; rr++) {
          const int m = m0 + wr + mt * 16 + fq * 4 + rr;
          const int n = n0 + wc + nt * 16 + fr;
          Y[(size_t)m * 512 + n] = f2bf(acc[mt][nt][rr]);
        }
  }
}

// ---------------------------------------------------------------------------
// score_gemm: raw scores = (q k^T)/sqrt(512) -> fp32 attn region, PLUS
// per-row partial sums of exp(score) into partial[slot][16384] (slot =
// by*2 + (wave&1), each (slot,row) written by exactly one thread — no
// atomics, deterministic). 128x128 tile, BK=32, dbuf 2-phase, A+B gload+swz.
// ---------------------------------------------------------------------------
__global__ __launch_bounds__(256) void score_gemm(
    const unsigned short* __restrict__ qb, const unsigned short* __restrict__ kb,
    float* __restrict__ attn, float* __restrict__ partial)
{
  __shared__ __align__(16) unsigned short As[2][128][32];
  __shared__ __align__(16) unsigned short Bs[2][128][32];

  const int tid = threadIdx.x, z = blockIdx.z;
  const int m0 = blockIdx.x * 128, n0 = blockIdx.y * 128;
  const int lane = tid & 63, wave = tid >> 6;
  const int wr = (wave >> 1) * 64, wc = (wave & 1) * 64;
  const int fr = lane & 15, fq = lane >> 4;

  f32x4 acc[4][4] = {};

  const int c1 = 256 + tid;
  const int br0 = tid >> 2, br1 = c1 >> 2;
  const int sw0 = ((tid & 3) ^ ((br0 >> 1) & 3)) * 8;
  const int sw1 = ((c1 & 3) ^ ((br1 >> 1) & 3)) * 8;
  const unsigned short* gA0 = qb + ((size_t)z * 1024 + m0 + br0) * 512 + sw0;
  const unsigned short* gA1 = qb + ((size_t)z * 1024 + m0 + br1) * 512 + sw1;
  const unsigned short* gB0 = kb + ((size_t)z * 1024 + n0 + br0) * 512 + sw0;
  const unsigned short* gB1 = kb + ((size_t)z * 1024 + n0 + br1) * 512 + sw1;
  char* lA0 = (char*)&As[0][0][0] + tid * 16;
  char* lA1 = (char*)&As[0][0][0] + c1 * 16;
  char* lB0 = (char*)&Bs[0][0][0] + tid * 16;
  char* lB1 = (char*)&Bs[0][0][0] + c1 * 16;

  gload16(gA0, lA0); gload16(gA1, lA1);
  gload16(gB0, lB0); gload16(gB1, lB1);
  __syncthreads();

  int cur = 0;
  for (int kt = 0; kt < 512 - 32; kt += 32) {
    const int nb = cur ^ 1;
    gload16(gA0 + kt + 32, lA0 + nb * 8192);
    gload16(gA1 + kt + 32, lA1 + nb * 8192);
    gload16(gB0 + kt + 32, lB0 + nb * 8192);
    gload16(gB1 + kt + 32, lB1 + nb * 8192);
    bf16x8 af[4], bv[4];
    #pragma unroll
    for (int t = 0; t < 4; t++) {
      const int arow = wr + t * 16 + fr;
      const int brow = wc + t * 16 + fr;
      af[t] = *(const bf16x8*)&As[cur][arow][(fq ^ ((arow >> 1) & 3)) * 8];
      bv[t] = *(const bf16x8*)&Bs[cur][brow][(fq ^ ((brow >> 1) & 3)) * 8];
    }
    #pragma unroll
    for (int mt = 0; mt < 4; mt++)
      #pragma unroll
      for (int nt = 0; nt < 4; nt++)
        acc[mt][nt] = __builtin_amdgcn_mfma_f32_16x16x32_bf16(af[mt], bv[nt], acc[mt][nt], 0, 0, 0);
    __syncthreads();
    cur = nb;
  }
  {
    bf16x8 af[4], bv[4];
    #pragma unroll
    for (int t = 0; t < 4; t++) {
      const int arow = wr + t * 16 + fr;
      const int brow = wc + t * 16 + fr;
      af[t] = *(const bf16x8*)&As[cur][arow][(fq ^ ((arow >> 1) & 3)) * 8];
      bv[t] = *(const bf16x8*)&Bs[cur][brow][(fq ^ ((brow >> 1) & 3)) * 8];
    }
    #pragma unroll
    for (int mt = 0; mt < 4; mt++)
      #pragma unroll
      for (int nt = 0; nt < 4; nt++)
        acc[mt][nt] = __builtin_amdgcn_mfma_f32_16x16x32_bf16(af[mt], bv[nt], acc[mt][nt], 0, 0, 0);
  }

  // epilogue: write raw scores + per-row exp partial sums
  float* Cb = attn + (size_t)z * 1024 * 1024;
  const int slot = blockIdx.y * 2 + (wave & 1);
  #pragma unroll
  for (int mt = 0; mt < 4; mt++) {
    #pragma unroll
    for (int rr = 0; rr < 4; rr++) {
      const int m = m0 + wr + mt * 16 + fq * 4 + rr;
      float e = 0.f;
      #pragma unroll
      for (int nt = 0; nt < 4; nt++) {
        const float sv = acc[mt][nt][rr] * SCALE_F;
        Cb[(size_t)m * 1024 + n0 + wc + nt * 16 + fr] = sv;
        e += __expf(sv);
      }
      e += __shfl_xor(e, 1); e += __shfl_xor(e, 2);
      e += __shfl_xor(e, 4); e += __shfl_xor(e, 8);
      if (fr == 0)
        partial[(size_t)slot * 16384 + z * 1024 + m] = e;
    }
  }
}

// ---------------------------------------------------------------------------
// rs_inv: inv[i] = 1 / sum_{s<16} partial[s][i]
// ---------------------------------------------------------------------------
__global__ __launch_bounds__(256) void rs_inv(
    const float* __restrict__ partial, float* __restrict__ inv)
{
  const int i = blockIdx.x * 256 + threadIdx.x;
  float s = 0.f;
  #pragma unroll
  for (int p = 0; p < 16; p++) s += partial[(size_t)p * 16384 + i];
  inv[i] = 1.0f / s;
}

// ---------------------------------------------------------------------------
// pv_gemm: out = attn_masked @ v, fused softmax-apply.
// Block owns 64 q-rows x ALL 512 out-cols (exclusive attn-row ownership):
// reads raw scores, p = mask ? exp(s)*inv : NEG_BIG; writes final attn fp32
// in place; p (bf16) -> LDS -> MFMA A operand. B = vt via gload+swz.
// 512 thr = 8 waves, wave tile 64x64, K=1024, BK=32.
// ---------------------------------------------------------------------------
__global__ __launch_bounds__(512) void pv_gemm(
    float* __restrict__ attn, const unsigned short* __restrict__ vt,
    const float* __restrict__ inv, const int* __restrict__ mask,
    float* __restrict__ out)
{
  __shared__ __align__(16) unsigned short As[64][40];
  __shared__ __align__(16) unsigned short Bs[512][32];

  const int tid = threadIdx.x;
  const int bz = blockIdx.z, m0 = blockIdx.x * 64;
  const int lane = tid & 63, wave = tid >> 6;
  const int n0 = wave * 64;
  const int fr = lane & 15, fq = lane >> 4;

  f32x4 acc[4][4] = {};

  const int arow = tid >> 3, acol = (tid & 7) * 4;
  float* arp = attn + ((size_t)bz * 1024 + m0 + arow) * 1024 + acol;
  const float vinv = inv[bz * 1024 + m0 + arow];
  const int* mrow = mask + bz * 1024 + acol;

  const unsigned short* gB[4];
  char* lB[4];
  #pragma unroll
  for (int r = 0; r < 4; r++) {
    const int c = r * 512 + tid;
    const int row = c >> 2;
    gB[r] = vt + ((size_t)bz * 512 + row) * 1024 + ((c & 3) ^ ((row >> 1) & 3)) * 8;
    lB[r] = (char*)&Bs[0][0] + c * 16;
  }

  for (int kt = 0; kt < 1024; kt += 32) {
    f32x4 s = *(const f32x4*)(arp + kt);
    i32x4 mv = *(const i32x4*)(mrow + kt);
    f32x4 p;
    p[0] = mv[0] ? __expf(s[0]) * vinv : NEG_BIG_F;
    p[1] = mv[1] ? __expf(s[1]) * vinv : NEG_BIG_F;
    p[2] = mv[2] ? __expf(s[2]) * vinv : NEG_BIG_F;
    p[3] = mv[3] ? __expf(s[3]) * vinv : NEG_BIG_F;
    *(f32x4*)(arp + kt) = p;                       // final attn, in place
    u16x4 h;
    h[0] = f2bf(p[0]); h[1] = f2bf(p[1]); h[2] = f2bf(p[2]); h[3] = f2bf(p[3]);
    *(u16x4*)&As[arow][acol] = h;
    #pragma unroll
    for (int r = 0; r < 4; r++) gload16(gB[r] + kt, lB[r]);
    __syncthreads();

    bf16x8 af[4], bv[4];
    #pragma unroll
    for (int t = 0; t < 4; t++) {
      af[t] = *(const bf16x8*)&As[t * 16 + fr][fq * 8];
      const int brow = n0 + t * 16 + fr;
      bv[t] = *(const bf16x8*)&Bs[brow][(fq ^ ((brow >> 1) & 3)) * 8];
    }
    #pragma unroll
    for (int mt = 0; mt < 4; mt++)
      #pragma unroll
      for (int nt = 0; nt < 4; nt++)
        acc[mt][nt] = __builtin_amdgcn_mfma_f32_16x16x32_bf16(af[mt], bv[nt], acc[mt][nt], 0, 0, 0);
    __syncthreads();
  }

  #pragma unroll
  for (int mt = 0; mt < 4; mt++)
    #pragma unroll
    for (int nt = 0; nt < 4; nt++)
      #pragma unroll
      for (int rr = 0; rr < 4; rr++)
        out[((size_t)bz * 1024 + m0 + mt * 16 + fq * 4 + rr) * 512 + n0 + nt * 16 + fr] =
            acc[mt][nt][rr];
}

// ---------------------------------------------------------------------------
extern "C" void kernel_launch(void* const* d_in, const int* in_sizes, int n_in,
                              void* d_out, int out_size, void* d_ws, size_t ws_size,
                              hipStream_t stream)
{
  const float* Q  = (const float*)d_in[0];
  const float* Kx = (const float*)d_in[1];
  const float* V  = (const float*)d_in[2];
  const float* WQ = (const float*)d_in[3];
  const float* WK = (const float*)d_in[4];
  const float* WV = (const float*)d_in[5];
  const int* mask = (const int*)d_in[6];

  const int B = 16, S = 1024, D = 512;
  float* out_f  = (float*)d_out;                 // B*S*D fp32
  float* attn_f = out_f + (size_t)B * S * D;     // B*S*S fp32 (scores -> attn)

  // ws: qb | kb | vt (8.39M ushorts each) | wb (0.79M) | partial | inv
  unsigned short* qb = (unsigned short*)d_ws;
  unsigned short* kb = qb + (size_t)B * S * D;
  unsigned short* vt = kb + (size_t)B * S * D;
  unsigned short* wb = vt + (size_t)B * S * D;
  float* partial = (float*)(wb + 786432);        // 16 x 16384 f32
  float* inv = partial + 262144;                 // 16384 f32

  cvtW<<<dim3(128, 1, 3), 256, 0, stream>>>(WQ, WK, WV, wb);
  proj3<<<dim3(128, 4, 3), 256, 0, stream>>>(Q, Kx, V, wb, qb, kb, vt);
  score_gemm<<<dim3(8, 8, 16), 256, 0, stream>>>(qb, kb, attn_f, partial);
  rs_inv<<<dim3(64), 256, 0, stream>>>(partial, inv);
  pv_gemm<<<dim3(16, 1, 16), 512, 0, stream>>>(attn_f, vt, inv, mask, out_f);
}

// Round 4
// 169.110 us; speedup vs baseline: 1.1001x; 1.0155x over previous
//
#include <hip/hip_runtime.h>
#include <hip/hip_bf16.h>

typedef float f32x4 __attribute__((ext_vector_type(4)));
typedef __bf16 bf16x8 __attribute__((ext_vector_type(8)));
typedef unsigned short u16x8 __attribute__((ext_vector_type(8)));
typedef unsigned short u16x4 __attribute__((ext_vector_type(4)));
typedef int i32x4 __attribute__((ext_vector_type(4)));

#define NEG_BIG_F (-1000000000.0f)
#define SCALE_F 0.044194173824159216f

__device__ __forceinline__ unsigned short f2bf(float f) {
  unsigned int u = __float_as_uint(f);
  u += 0x7FFFu + ((u >> 16) & 1u);   // round-to-nearest-even
  return (unsigned short)(u >> 16);
}

__device__ __forceinline__ u16x8 cvt8(f32x4 a, f32x4 b) {
  u16x8 r;
  r[0] = f2bf(a[0]); r[1] = f2bf(a[1]); r[2] = f2bf(a[2]); r[3] = f2bf(a[3]);
  r[4] = f2bf(b[0]); r[5] = f2bf(b[1]); r[6] = f2bf(b[2]); r[7] = f2bf(b[3]);
  return r;
}

__device__ __forceinline__ bf16x8 u2b(u16x8 u) {
  union { u16x8 u; bf16x8 b; } c; c.u = u; return c.b;
}

__device__ __forceinline__ void gload16(const void* g, char* l) {
  __builtin_amdgcn_global_load_lds(
      (const __attribute__((address_space(1))) unsigned int*)g,
      (__attribute__((address_space(3))) unsigned int*)l, 16, 0, 0);
}

// ---------------------------------------------------------------------------
// cvtW: three 512x512 fp32 weight matrices -> bf16
// ---------------------------------------------------------------------------
__global__ __launch_bounds__(256) void cvtW(
    const float* __restrict__ w0, const float* __restrict__ w1,
    const float* __restrict__ w2, unsigned short* __restrict__ out)
{
  const float* src = blockIdx.z == 0 ? w0 : (blockIdx.z == 1 ? w1 : w2);
  unsigned short* dst = out + (size_t)blockIdx.z * 262144;
  const int i = (blockIdx.x * 256 + threadIdx.x) * 8;
  f32x4 a = *(const f32x4*)(src + i);
  f32x4 b = *(const f32x4*)(src + i + 4);
  *(u16x8*)&dst[i] = cvt8(a, b);
}

// ---------------------------------------------------------------------------
// proj3: all three projections (z = 0:Q 1:K 2:V), 128x128 tile, BK=32.
// A = fp32 activations staged via global_load_lds into an fp32 LDS tile
// (16B-slot XOR swizzle, both-sides), converted to bf16 AT FRAGMENT READ.
// B = bf16 weights via global_load_lds (4-slot XOR swizzle).
// 2-phase dbuf: all staging loads for kt+32 issued before compute(kt).
// ---------------------------------------------------------------------------
__global__ __launch_bounds__(256) void proj3(
    const float* __restrict__ Q, const float* __restrict__ Kx,
    const float* __restrict__ V, const unsigned short* __restrict__ wb,
    unsigned short* __restrict__ qb, unsigned short* __restrict__ kb,
    unsigned short* __restrict__ vt)
{
  __shared__ __align__(16) float          Af[2][128][32];  // 32 KB
  __shared__ __align__(16) unsigned short Bs[2][128][32];  // 16 KB

  const int tid = threadIdx.x;
  const int z = blockIdx.z;
  const float* X = (z == 0) ? Q : (z == 1 ? Kx : V);
  const unsigned short* W = wb + (size_t)z * 262144;
  const int m0 = blockIdx.x * 128, n0 = blockIdx.y * 128;
  const int lane = tid & 63, wave = tid >> 6;
  const int wr = (wave >> 1) * 64, wc = (wave & 1) * 64;
  const int fr = lane & 15, fq = lane >> 4;

  f32x4 acc[4][4] = {};

  // A: 1024 16B-chunks (8 per row of 32 f32). chunk c: row=c>>3, slot=c&7,
  // source col pre-swizzled so LDS slot j holds global slot j^(row&7).
  const float* gA[4]; char* lA[4];
  #pragma unroll
  for (int i = 0; i < 4; i++) {
    const int c = tid + 256 * i, row = c >> 3, slot = c & 7;
    gA[i] = X + (size_t)(m0 + row) * 512 + ((slot ^ (row & 7)) * 4);
    lA[i] = (char*)&Af[0][0][0] + c * 16;
  }
  // B: 512 16B-chunks (4 per row of 32 bf16), 4-slot XOR by (row>>1)&3.
  const int c1 = 256 + tid;
  const int br0 = tid >> 2, br1 = c1 >> 2;
  const unsigned short* gB0 = W + (size_t)(n0 + br0) * 512 + ((tid & 3) ^ ((br0 >> 1) & 3)) * 8;
  const unsigned short* gB1 = W + (size_t)(n0 + br1) * 512 + ((c1 & 3) ^ ((br1 >> 1) & 3)) * 8;
  char* lB0 = (char*)&Bs[0][0][0] + tid * 16;
  char* lB1 = (char*)&Bs[0][0][0] + c1 * 16;

  #pragma unroll
  for (int i = 0; i < 4; i++) gload16(gA[i], lA[i]);
  gload16(gB0, lB0); gload16(gB1, lB1);
  __syncthreads();

  int cur = 0;
  for (int kt = 0; kt < 512; kt += 32) {
    const int nb = cur ^ 1;
    if (kt + 32 < 512) {
      #pragma unroll
      for (int i = 0; i < 4; i++) gload16(gA[i] + kt + 32, lA[i] + nb * 16384);
      gload16(gB0 + kt + 32, lB0 + nb * 8192);
      gload16(gB1 + kt + 32, lB1 + nb * 8192);
    }
    bf16x8 af[4], bv[4];
    #pragma unroll
    for (int t = 0; t < 4; t++) {
      const int arow = wr + t * 16 + fr;
      const int s0 = (fq * 2) ^ (arow & 7), s1 = (fq * 2 + 1) ^ (arow & 7);
      f32x4 lo = *(const f32x4*)&Af[cur][arow][s0 * 4];
      f32x4 hi = *(const f32x4*)&Af[cur][arow][s1 * 4];
      af[t] = u2b(cvt8(lo, hi));
      const int brow = wc + t * 16 + fr;
      bv[t] = *(const bf16x8*)&Bs[cur][brow][(fq ^ ((brow >> 1) & 3)) * 8];
    }
    #pragma unroll
    for (int mt = 0; mt < 4; mt++)
      #pragma unroll
      for (int nt = 0; nt < 4; nt++)
        acc[mt][nt] = __builtin_amdgcn_mfma_f32_16x16x32_bf16(af[mt], bv[nt], acc[mt][nt], 0, 0, 0);
    __syncthreads();
    cur = nb;
  }

  if (z == 2) {
    #pragma unroll
    for (int mt = 0; mt < 4; mt++)
      #pragma unroll
      for (int nt = 0; nt < 4; nt++)
        #pragma unroll
        for (int rr = 0; rr < 4; rr++) {
          const int m = m0 + wr + mt * 16 + fq * 4 + rr;
          const int n = n0 + wc + nt * 16 + fr;
          vt[((size_t)(m >> 10) * 512 + n) * 1024 + (m & 1023)] = f2bf(acc[mt][nt][rr]);
        }
  } else {
    unsigned short* Y = (z == 0) ? qb : kb;
    #pragma unroll
    for (int mt = 0; mt < 4; mt++)
      #pragma unroll
      for (int nt = 0; nt < 4; nt++)
        #pragma unroll
        for (int rr = 0; rr < 4; rr++) {
          const int m = m0 + wr + mt * 16 + fq * 4 + rr;
          const int n = n0 + wc + nt * 16 + fr;
          Y[(size_t)m * 512 + n] = f2bf(acc[mt][nt][rr]);
        }
  }
}

// ---------------------------------------------------------------------------
// score_gemm: raw scores = (q k^T)/sqrt(512) -> fp32 attn region, PLUS
// per-row partial sums of exp(score) (slot = by*2 + (wave&1); each
// (slot,row) written by exactly one thread). dbuf 2-phase, A+B gload+swz.
// ---------------------------------------------------------------------------
__global__ __launch_bounds__(256) void score_gemm(
    const unsigned short* __restrict__ qb, const unsigned short* __restrict__ kb,
    float* __restrict__ attn, float* __restrict__ partial)
{
  __shared__ __align__(16) unsigned short As[2][128][32];
  __shared__ __align__(16) unsigned short Bs[2][128][32];

  const int tid = threadIdx.x, z = blockIdx.z;
  const int m0 = blockIdx.x * 128, n0 = blockIdx.y * 128;
  const int lane = tid & 63, wave = tid >> 6;
  const int wr = (wave >> 1) * 64, wc = (wave & 1) * 64;
  const int fr = lane & 15, fq = lane >> 4;

  f32x4 acc[4][4] = {};

  const int c1 = 256 + tid;
  const int br0 = tid >> 2, br1 = c1 >> 2;
  const int sw0 = ((tid & 3) ^ ((br0 >> 1) & 3)) * 8;
  const int sw1 = ((c1 & 3) ^ ((br1 >> 1) & 3)) * 8;
  const unsigned short* gA0 = qb + ((size_t)z * 1024 + m0 + br0) * 512 + sw0;
  const unsigned short* gA1 = qb + ((size_t)z * 1024 + m0 + br1) * 512 + sw1;
  const unsigned short* gB0 = kb + ((size_t)z * 1024 + n0 + br0) * 512 + sw0;
  const unsigned short* gB1 = kb + ((size_t)z * 1024 + n0 + br1) * 512 + sw1;
  char* lA0 = (char*)&As[0][0][0] + tid * 16;
  char* lA1 = (char*)&As[0][0][0] + c1 * 16;
  char* lB0 = (char*)&Bs[0][0][0] + tid * 16;
  char* lB1 = (char*)&Bs[0][0][0] + c1 * 16;

  gload16(gA0, lA0); gload16(gA1, lA1);
  gload16(gB0, lB0); gload16(gB1, lB1);
  __syncthreads();

  int cur = 0;
  for (int kt = 0; kt < 512; kt += 32) {
    const int nb = cur ^ 1;
    if (kt + 32 < 512) {
      gload16(gA0 + kt + 32, lA0 + nb * 8192);
      gload16(gA1 + kt + 32, lA1 + nb * 8192);
      gload16(gB0 + kt + 32, lB0 + nb * 8192);
      gload16(gB1 + kt + 32, lB1 + nb * 8192);
    }
    bf16x8 af[4], bv[4];
    #pragma unroll
    for (int t = 0; t < 4; t++) {
      const int arow = wr + t * 16 + fr;
      const int brow = wc + t * 16 + fr;
      af[t] = *(const bf16x8*)&As[cur][arow][(fq ^ ((arow >> 1) & 3)) * 8];
      bv[t] = *(const bf16x8*)&Bs[cur][brow][(fq ^ ((brow >> 1) & 3)) * 8];
    }
    #pragma unroll
    for (int mt = 0; mt < 4; mt++)
      #pragma unroll
      for (int nt = 0; nt < 4; nt++)
        acc[mt][nt] = __builtin_amdgcn_mfma_f32_16x16x32_bf16(af[mt], bv[nt], acc[mt][nt], 0, 0, 0);
    __syncthreads();
    cur = nb;
  }

  float* Cb = attn + (size_t)z * 1024 * 1024;
  const int slot = blockIdx.y * 2 + (wave & 1);
  #pragma unroll
  for (int mt = 0; mt < 4; mt++) {
    #pragma unroll
    for (int rr = 0; rr < 4; rr++) {
      const int m = m0 + wr + mt * 16 + fq * 4 + rr;
      float e = 0.f;
      #pragma unroll
      for (int nt = 0; nt < 4; nt++) {
        const float sv = acc[mt][nt][rr] * SCALE_F;
        Cb[(size_t)m * 1024 + n0 + wc + nt * 16 + fr] = sv;
        e += __expf(sv);
      }
      e += __shfl_xor(e, 1); e += __shfl_xor(e, 2);
      e += __shfl_xor(e, 4); e += __shfl_xor(e, 8);
      if (fr == 0)
        partial[(size_t)slot * 16384 + z * 1024 + m] = e;
    }
  }
}

// ---------------------------------------------------------------------------
// rs_inv: inv[i] = 1 / sum_{s<16} partial[s][i]
// ---------------------------------------------------------------------------
__global__ __launch_bounds__(256) void rs_inv(
    const float* __restrict__ partial, float* __restrict__ inv)
{
  const int i = blockIdx.x * 256 + threadIdx.x;
  float s = 0.f;
  #pragma unroll
  for (int p = 0; p < 16; p++) s += partial[(size_t)p * 16384 + i];
  inv[i] = 1.0f / s;
}

// ---------------------------------------------------------------------------
// pv_gemm: out = attn_masked @ v, fused softmax-apply, 2-phase dbuf.
// Block owns 64 q-rows x all 512 cols; per K-step: prefetch scores/mask to
// regs + issue B gloads (nb) BEFORE the MFMA phase; exp/attn-write/ds_write
// AFTER it. Writes final attn fp32 in place. 512 thr = 8 waves.
// ---------------------------------------------------------------------------
__global__ __launch_bounds__(512) void pv_gemm(
    float* __restrict__ attn, const unsigned short* __restrict__ vt,
    const float* __restrict__ inv, const int* __restrict__ mask,
    float* __restrict__ out)
{
  __shared__ __align__(16) unsigned short As[2][64][40];   // 10 KB
  __shared__ __align__(16) unsigned short Bs[2][512][32];  // 64 KB

  const int tid = threadIdx.x;
  const int bz = blockIdx.z, m0 = blockIdx.x * 64;
  const int lane = tid & 63, wave = tid >> 6;
  const int n0 = wave * 64;
  const int fr = lane & 15, fq = lane >> 4;

  f32x4 acc[4][4] = {};

  const int arow = tid >> 3, acol = (tid & 7) * 4;
  float* arp = attn + ((size_t)bz * 1024 + m0 + arow) * 1024 + acol;
  const float vinv = inv[bz * 1024 + m0 + arow];
  const int* mrow = mask + bz * 1024 + acol;

  const unsigned short* gB[4];
  char* lB[4];
  #pragma unroll
  for (int r = 0; r < 4; r++) {
    const int c = r * 512 + tid;
    const int row = c >> 2;
    gB[r] = vt + ((size_t)bz * 512 + row) * 1024 + ((c & 3) ^ ((row >> 1) & 3)) * 8;
    lB[r] = (char*)&Bs[0][0][0] + c * 16;
  }

  // prologue: stage kt=0 into buffer 0
  {
    f32x4 s = *(const f32x4*)(arp);
    i32x4 mv = *(const i32x4*)(mrow);
    f32x4 p;
    p[0] = mv[0] ? __expf(s[0]) * vinv : NEG_BIG_F;
    p[1] = mv[1] ? __expf(s[1]) * vinv : NEG_BIG_F;
    p[2] = mv[2] ? __expf(s[2]) * vinv : NEG_BIG_F;
    p[3] = mv[3] ? __expf(s[3]) * vinv : NEG_BIG_F;
    *(f32x4*)(arp) = p;
    u16x4 h;
    h[0] = f2bf(p[0]); h[1] = f2bf(p[1]); h[2] = f2bf(p[2]); h[3] = f2bf(p[3]);
    *(u16x4*)&As[0][arow][acol] = h;
    #pragma unroll
    for (int r = 0; r < 4; r++) gload16(gB[r], lB[r]);
  }
  __syncthreads();

  int cur = 0;
  for (int kt = 0; kt < 1024; kt += 32) {
    const int nb = cur ^ 1;
    f32x4 s; i32x4 mv;
    const bool more = (kt + 32) < 1024;
    if (more) {
      s = *(const f32x4*)(arp + kt + 32);
      mv = *(const i32x4*)(mrow + kt + 32);
      #pragma unroll
      for (int r = 0; r < 4; r++) gload16(gB[r] + kt + 32, lB[r] + nb * 32768);
    }

    bf16x8 af[4], bv[4];
    #pragma unroll
    for (int t = 0; t < 4; t++) {
      af[t] = *(const bf16x8*)&As[cur][t * 16 + fr][fq * 8];
      const int brow = n0 + t * 16 + fr;
      bv[t] = *(const bf16x8*)&Bs[cur][brow][(fq ^ ((brow >> 1) & 3)) * 8];
    }
    #pragma unroll
    for (int mt = 0; mt < 4; mt++)
      #pragma unroll
      for (int nt = 0; nt < 4; nt++)
        acc[mt][nt] = __builtin_amdgcn_mfma_f32_16x16x32_bf16(af[mt], bv[nt], acc[mt][nt], 0, 0, 0);

    if (more) {
      f32x4 p;
      p[0] = mv[0] ? __expf(s[0]) * vinv : NEG_BIG_F;
      p[1] = mv[1] ? __expf(s[1]) * vinv : NEG_BIG_F;
      p[2] = mv[2] ? __expf(s[2]) * vinv : NEG_BIG_F;
      p[3] = mv[3] ? __expf(s[3]) * vinv : NEG_BIG_F;
      *(f32x4*)(arp + kt + 32) = p;
      u16x4 h;
      h[0] = f2bf(p[0]); h[1] = f2bf(p[1]); h[2] = f2bf(p[2]); h[3] = f2bf(p[3]);
      *(u16x4*)&As[nb][arow][acol] = h;
    }
    __syncthreads();
    cur = nb;
  }

  #pragma unroll
  for (int mt = 0; mt < 4; mt++)
    #pragma unroll
    for (int nt = 0; nt < 4; nt++)
      #pragma unroll
      for (int rr = 0; rr < 4; rr++)
        out[((size_t)bz * 1024 + m0 + mt * 16 + fq * 4 + rr) * 512 + n0 + nt * 16 + fr] =
            acc[mt][nt][rr];
}

// ---------------------------------------------------------------------------
extern "C" void kernel_launch(void* const* d_in, const int* in_sizes, int n_in,
                              void* d_out, int out_size, void* d_ws, size_t ws_size,
                              hipStream_t stream)
{
  const float* Q  = (const float*)d_in[0];
  const float* Kx = (const float*)d_in[1];
  const float* V  = (const float*)d_in[2];
  const float* WQ = (const float*)d_in[3];
  const float* WK = (const float*)d_in[4];
  const float* WV = (const float*)d_in[5];
  const int* mask = (const int*)d_in[6];

  const int B = 16, S = 1024, D = 512;
  float* out_f  = (float*)d_out;                 // B*S*D fp32
  float* attn_f = out_f + (size_t)B * S * D;     // B*S*S fp32 (scores -> attn)

  // ws: qb | kb | vt (8.39M ushorts each) | wb (0.79M) | partial | inv
  unsigned short* qb = (unsigned short*)d_ws;
  unsigned short* kb = qb + (size_t)B * S * D;
  unsigned short* vt = kb + (size_t)B * S * D;
  unsigned short* wb = vt + (size_t)B * S * D;
  float* partial = (float*)(wb + 786432);        // 16 x 16384 f32
  float* inv = partial + 262144;                 // 16384 f32

  cvtW<<<dim3(128, 1, 3), 256, 0, stream>>>(WQ, WK, WV, wb);
  proj3<<<dim3(128, 4, 3), 256, 0, stream>>>(Q, Kx, V, wb, qb, kb, vt);
  score_gemm<<<dim3(8, 8, 16), 256, 0, stream>>>(qb, kb, attn_f, partial);
  rs_inv<<<dim3(64), 256, 0, stream>>>(partial, inv);
  pv_gemm<<<dim3(16, 1, 16), 512, 0, stream>>>(attn_f, vt, inv, mask, out_f);
}

// Round 6
// 163.530 us; speedup vs baseline: 1.1376x; 1.0341x over previous
//
#include <hip/hip_runtime.h>
#include <hip/hip_bf16.h>

typedef float f32x4 __attribute__((ext_vector_type(4)));
typedef __bf16 bf16x8 __attribute__((ext_vector_type(8)));
typedef unsigned short u16x8 __attribute__((ext_vector_type(8)));
typedef unsigned short u16x4 __attribute__((ext_vector_type(4)));
typedef int i32x4 __attribute__((ext_vector_type(4)));

#define NEG_BIG_F (-1000000000.0f)
#define SCALE_F 0.044194173824159216f

__device__ __forceinline__ unsigned short f2bf(float f) {
  unsigned int u = __float_as_uint(f);
  u += 0x7FFFu + ((u >> 16) & 1u);   // round-to-nearest-even
  return (unsigned short)(u >> 16);
}

__device__ __forceinline__ u16x8 cvt8(f32x4 a, f32x4 b) {
  u16x8 r;
  r[0] = f2bf(a[0]); r[1] = f2bf(a[1]); r[2] = f2bf(a[2]); r[3] = f2bf(a[3]);
  r[4] = f2bf(b[0]); r[5] = f2bf(b[1]); r[6] = f2bf(b[2]); r[7] = f2bf(b[3]);
  return r;
}

__device__ __forceinline__ bf16x8 u2b(u16x8 u) {
  union { u16x8 u; bf16x8 b; } c; c.u = u; return c.b;
}

__device__ __forceinline__ void gload16(const void* g, char* l) {
  __builtin_amdgcn_global_load_lds(
      (const __attribute__((address_space(1))) unsigned int*)g,
      (__attribute__((address_space(3))) unsigned int*)l, 16, 0, 0);
}

// ---------------------------------------------------------------------------
// cvtW: three 512x512 fp32 weight matrices -> bf16
// ---------------------------------------------------------------------------
__global__ __launch_bounds__(256) void cvtW(
    const float* __restrict__ w0, const float* __restrict__ w1,
    const float* __restrict__ w2, unsigned short* __restrict__ out)
{
  const float* src = blockIdx.z == 0 ? w0 : (blockIdx.z == 1 ? w1 : w2);
  unsigned short* dst = out + (size_t)blockIdx.z * 262144;
  const int i = (blockIdx.x * 256 + threadIdx.x) * 8;
  f32x4 a = *(const f32x4*)(src + i);
  f32x4 b = *(const f32x4*)(src + i + 4);
  *(u16x8*)&dst[i] = cvt8(a, b);
}

// ---------------------------------------------------------------------------
// projqk: z=0: qb = Q·WQ^T, z=1: kb = K·WK^T. 256x256 tile, BK=32, 512 thr
// (8 waves as 2x4; wave tile 128x64). Counted-vmcnt two-barrier loop:
// loads for tile t+1 issued before the waits for tile t; vmcnt never
// drained to 0 mid-loop. A = fp32 reg-staged (issue-early, ds_write-late,
// bf16 in LDS with 4-slot XOR swizzle). B = bf16 via global_load_lds
// (linear dest, inverse-swizzled source).  LDS 64 KB.
// ---------------------------------------------------------------------------
__global__ __launch_bounds__(512, 2) void projqk(
    const float* __restrict__ Q, const float* __restrict__ Kx,
    const unsigned short* __restrict__ wb,
    unsigned short* __restrict__ qb, unsigned short* __restrict__ kb)
{
  __shared__ __align__(16) unsigned short As[2][256][32];  // 32 KB
  __shared__ __align__(16) unsigned short Bs[2][256][32];  // 32 KB

  const int tid = threadIdx.x, z = blockIdx.z;
  const float* X = z ? Kx : Q;
  const unsigned short* W = wb + (size_t)z * 262144;
  unsigned short* Y = z ? kb : qb;
  const int m0 = blockIdx.x * 256, n0 = blockIdx.y * 256;
  const int lane = tid & 63, wave = tid >> 6;
  const int wr = (wave >> 2) * 128, wc = (wave & 3) * 64;
  const int fr = lane & 15, fq = lane >> 4;

  f32x4 acc[8][4] = {};

  // A reg-stage: 2 granule-pairs/thread. pair i: c=tid+512i, row=c>>2, slot=c&3
  int arow_s[2], aswz_s[2];
  const float* gAs[2];
  #pragma unroll
  for (int i = 0; i < 2; i++) {
    const int c = tid + 512 * i;
    arow_s[i] = c >> 2;
    aswz_s[i] = ((c & 3) ^ ((arow_s[i] >> 1) & 3)) * 8;
    gAs[i] = X + (size_t)(m0 + arow_s[i]) * 512 + (c & 3) * 8;
  }
  // B gload: 2 chunks/thread, pre-swizzled source
  const unsigned short* gB[2]; char* lB[2];
  #pragma unroll
  for (int i = 0; i < 2; i++) {
    const int c = tid + 512 * i, row = c >> 2, slot = c & 3;
    gB[i] = W + (size_t)(n0 + row) * 512 + (slot ^ ((row >> 1) & 3)) * 8;
    lB[i] = (char*)&Bs[0][0][0] + c * 16;
  }

  // prologue: stage kt=0 into buf 0
  f32x4 pa[2][2];
  #pragma unroll
  for (int i = 0; i < 2; i++) {
    pa[i][0] = *(const f32x4*)(gAs[i]);
    pa[i][1] = *(const f32x4*)(gAs[i] + 4);
  }
  #pragma unroll
  for (int i = 0; i < 2; i++) gload16(gB[i], lB[i]);
  #pragma unroll
  for (int i = 0; i < 2; i++)
    *(u16x8*)&As[0][arow_s[i]][aswz_s[i]] = cvt8(pa[i][0], pa[i][1]);

  int cur = 0;
  for (int kt = 0; kt < 512; kt += 32) {
    const int nb = cur ^ 1;
    if (kt < 480) {
      #pragma unroll
      for (int i = 0; i < 2; i++) {
        pa[i][0] = *(const f32x4*)(gAs[i] + kt + 32);
        pa[i][1] = *(const f32x4*)(gAs[i] + kt + 36);
      }
      #pragma unroll
      for (int i = 0; i < 2; i++) gload16(gB[i] + kt + 32, lB[i] + nb * 16384);
      asm volatile("s_waitcnt vmcnt(6) lgkmcnt(0)" ::: "memory");
    } else {
      asm volatile("s_waitcnt vmcnt(0) lgkmcnt(0)" ::: "memory");
    }
    __builtin_amdgcn_sched_barrier(0);
    __builtin_amdgcn_s_barrier();

    bf16x8 bv[4];
    #pragma unroll
    for (int nf = 0; nf < 4; nf++) {
      const int br = wc + nf * 16 + fr;
      bv[nf] = *(const bf16x8*)&Bs[cur][br][(fq ^ ((br >> 1) & 3)) * 8];
    }
    #pragma unroll
    for (int mf = 0; mf < 8; mf++) {
      const int ar = wr + mf * 16 + fr;
      bf16x8 av = *(const bf16x8*)&As[cur][ar][(fq ^ ((ar >> 1) & 3)) * 8];
      #pragma unroll
      for (int nf = 0; nf < 4; nf++)
        acc[mf][nf] = __builtin_amdgcn_mfma_f32_16x16x32_bf16(av, bv[nf], acc[mf][nf], 0, 0, 0);
    }

    if (kt < 480) {   // write-late: A regs -> LDS nb (compiler waits the loads)
      #pragma unroll
      for (int i = 0; i < 2; i++)
        *(u16x8*)&As[nb][arow_s[i]][aswz_s[i]] = cvt8(pa[i][0], pa[i][1]);
    }
    __builtin_amdgcn_s_barrier();
    cur = nb;
  }

  #pragma unroll
  for (int mf = 0; mf < 8; mf++)
    #pragma unroll
    for (int nf = 0; nf < 4; nf++)
      #pragma unroll
      for (int rr = 0; rr < 4; rr++) {
        const int m = m0 + wr + mf * 16 + fq * 4 + rr;
        const int n = n0 + wc + nf * 16 + fr;
        Y[(size_t)m * 512 + n] = f2bf(acc[mf][nf][rr]);
      }
}

// ---------------------------------------------------------------------------
// projv: vt[b][e][s] = sum_d WV[e][d] * V[b][s][d]  (A = WV bf16, B = V fp32)
// 128(e) x 256(s) tile, BK=32, 512 thr (waves 2x4, wave tile 64x64).
// A via global_load_lds; B reg-staged fp32 -> bf16 LDS. Coalesced epilogue.
// grid (4,4,16) = 256 blocks. LDS 48 KB.
// R6 FIX: A dbuf stride is 8192 B (128*32*2), NOT 4096 — R5 wrote the
// second buffer into the middle of buffer 0 (race + garbage vt).
// ---------------------------------------------------------------------------
__global__ __launch_bounds__(512, 2) void projv(
    const float* __restrict__ V, const unsigned short* __restrict__ wv,
    unsigned short* __restrict__ vt)
{
  __shared__ __align__(16) unsigned short As[2][128][32];  // 16 KB
  __shared__ __align__(16) unsigned short Bs[2][256][32];  // 32 KB

  const int tid = threadIdx.x;
  const int m0 = blockIdx.x * 128, n0 = blockIdx.y * 256, b = blockIdx.z;
  const int lane = tid & 63, wave = tid >> 6;
  const int wr = (wave >> 2) * 64, wc = (wave & 3) * 64;
  const int fr = lane & 15, fq = lane >> 4;

  f32x4 acc[4][4] = {};

  // A: 1 chunk/thread via gload (pre-swizzled source)
  const int ar_s = tid >> 2, aslot = tid & 3;
  const unsigned short* gA = wv + (size_t)(m0 + ar_s) * 512 + (aslot ^ ((ar_s >> 1) & 3)) * 8;
  char* lA = (char*)&As[0][0][0] + tid * 16;

  // B reg-stage: 2 granule-pairs/thread
  int brow_s[2], bswz_s[2];
  const float* gBs[2];
  #pragma unroll
  for (int i = 0; i < 2; i++) {
    const int c = tid + 512 * i;
    brow_s[i] = c >> 2;
    bswz_s[i] = ((c & 3) ^ ((brow_s[i] >> 1) & 3)) * 8;
    gBs[i] = V + ((size_t)b * 1024 + n0 + brow_s[i]) * 512 + (c & 3) * 8;
  }

  // prologue
  f32x4 pb[2][2];
  #pragma unroll
  for (int i = 0; i < 2; i++) {
    pb[i][0] = *(const f32x4*)(gBs[i]);
    pb[i][1] = *(const f32x4*)(gBs[i] + 4);
  }
  gload16(gA, lA);
  #pragma unroll
  for (int i = 0; i < 2; i++)
    *(u16x8*)&Bs[0][brow_s[i]][bswz_s[i]] = cvt8(pb[i][0], pb[i][1]);

  int cur = 0;
  for (int kt = 0; kt < 512; kt += 32) {
    const int nb = cur ^ 1;
    if (kt < 480) {
      #pragma unroll
      for (int i = 0; i < 2; i++) {
        pb[i][0] = *(const f32x4*)(gBs[i] + kt + 32);
        pb[i][1] = *(const f32x4*)(gBs[i] + kt + 36);
      }
      gload16(gA + kt + 32, lA + nb * 8192);   // FIX: buffer stride 8192 B
      asm volatile("s_waitcnt vmcnt(5) lgkmcnt(0)" ::: "memory");
    } else {
      asm volatile("s_waitcnt vmcnt(0) lgkmcnt(0)" ::: "memory");
    }
    __builtin_amdgcn_sched_barrier(0);
    __builtin_amdgcn_s_barrier();

    bf16x8 av[4], bv[4];
    #pragma unroll
    for (int mf = 0; mf < 4; mf++) {
      const int ar = wr + mf * 16 + fr;
      av[mf] = *(const bf16x8*)&As[cur][ar][(fq ^ ((ar >> 1) & 3)) * 8];
    }
    #pragma unroll
    for (int nf = 0; nf < 4; nf++) {
      const int br = wc + nf * 16 + fr;
      bv[nf] = *(const bf16x8*)&Bs[cur][br][(fq ^ ((br >> 1) & 3)) * 8];
    }
    #pragma unroll
    for (int mf = 0; mf < 4; mf++)
      #pragma unroll
      for (int nf = 0; nf < 4; nf++)
        acc[mf][nf] = __builtin_amdgcn_mfma_f32_16x16x32_bf16(av[mf], bv[nf], acc[mf][nf], 0, 0, 0);

    if (kt < 480) {
      #pragma unroll
      for (int i = 0; i < 2; i++)
        *(u16x8*)&Bs[nb][brow_s[i]][bswz_s[i]] = cvt8(pb[i][0], pb[i][1]);
    }
    __builtin_amdgcn_s_barrier();
    cur = nb;
  }

  #pragma unroll
  for (int mf = 0; mf < 4; mf++)
    #pragma unroll
    for (int nf = 0; nf < 4; nf++)
      #pragma unroll
      for (int rr = 0; rr < 4; rr++) {
        const int e = m0 + wr + mf * 16 + fq * 4 + rr;
        const int s = n0 + wc + nf * 16 + fr;
        vt[((size_t)b * 512 + e) * 1024 + s] = f2bf(acc[mf][nf][rr]);
      }
}

// ---------------------------------------------------------------------------
// score256: raw scores = (q k^T)/sqrt(512) -> fp32 attn region + per-row
// partial exp-sums (16 slots: by*4 + (wave&3); one writer per (slot,row)).
// 256x256 tile, BK=32, both operands bf16 via global_load_lds, counted vmcnt.
// grid (4,4,16) = 256 blocks. LDS 64 KB.
// ---------------------------------------------------------------------------
__global__ __launch_bounds__(512, 2) void score256(
    const unsigned short* __restrict__ qb, const unsigned short* __restrict__ kb,
    float* __restrict__ attn, float* __restrict__ partial)
{
  __shared__ __align__(16) unsigned short As[2][256][32];
  __shared__ __align__(16) unsigned short Bs[2][256][32];

  const int tid = threadIdx.x, bz = blockIdx.z;
  const int m0 = blockIdx.x * 256, n0 = blockIdx.y * 256;
  const int lane = tid & 63, wave = tid >> 6;
  const int wr = (wave >> 2) * 128, wc = (wave & 3) * 64;
  const int fr = lane & 15, fq = lane >> 4;

  f32x4 acc[8][4] = {};

  const unsigned short* gA[2]; char* lA[2];
  const unsigned short* gB[2]; char* lB[2];
  #pragma unroll
  for (int i = 0; i < 2; i++) {
    const int c = tid + 512 * i, row = c >> 2, slot = c & 3;
    const int sw = (slot ^ ((row >> 1) & 3)) * 8;
    gA[i] = qb + ((size_t)bz * 1024 + m0 + row) * 512 + sw;
    gB[i] = kb + ((size_t)bz * 1024 + n0 + row) * 512 + sw;
    lA[i] = (char*)&As[0][0][0] + c * 16;
    lB[i] = (char*)&Bs[0][0][0] + c * 16;
  }

  #pragma unroll
  for (int i = 0; i < 2; i++) { gload16(gA[i], lA[i]); gload16(gB[i], lB[i]); }

  int cur = 0;
  for (int kt = 0; kt < 512; kt += 32) {
    const int nb = cur ^ 1;
    if (kt < 480) {
      #pragma unroll
      for (int i = 0; i < 2; i++) {
        gload16(gA[i] + kt + 32, lA[i] + nb * 16384);
        gload16(gB[i] + kt + 32, lB[i] + nb * 16384);
      }
      asm volatile("s_waitcnt vmcnt(4) lgkmcnt(0)" ::: "memory");
    } else {
      asm volatile("s_waitcnt vmcnt(0) lgkmcnt(0)" ::: "memory");
    }
    __builtin_amdgcn_sched_barrier(0);
    __builtin_amdgcn_s_barrier();

    bf16x8 bv[4];
    #pragma unroll
    for (int nf = 0; nf < 4; nf++) {
      const int br = wc + nf * 16 + fr;
      bv[nf] = *(const bf16x8*)&Bs[cur][br][(fq ^ ((br >> 1) & 3)) * 8];
    }
    #pragma unroll
    for (int mf = 0; mf < 8; mf++) {
      const int ar = wr + mf * 16 + fr;
      bf16x8 av = *(const bf16x8*)&As[cur][ar][(fq ^ ((ar >> 1) & 3)) * 8];
      #pragma unroll
      for (int nf = 0; nf < 4; nf++)
        acc[mf][nf] = __builtin_amdgcn_mfma_f32_16x16x32_bf16(av, bv[nf], acc[mf][nf], 0, 0, 0);
    }
    __builtin_amdgcn_s_barrier();
    cur = nb;
  }

  float* Cb = attn + (size_t)bz * 1024 * 1024;
  const int slot = blockIdx.y * 4 + (wave & 3);
  #pragma unroll
  for (int mf = 0; mf < 8; mf++) {
    #pragma unroll
    for (int rr = 0; rr < 4; rr++) {
      const int m = m0 + wr + mf * 16 + fq * 4 + rr;
      float e = 0.f;
      #pragma unroll
      for (int nf = 0; nf < 4; nf++) {
        const float sv = acc[mf][nf][rr] * SCALE_F;
        Cb[(size_t)m * 1024 + n0 + wc + nf * 16 + fr] = sv;
        e += __expf(sv);
      }
      e += __shfl_xor(e, 1); e += __shfl_xor(e, 2);
      e += __shfl_xor(e, 4); e += __shfl_xor(e, 8);
      if (fr == 0)
        partial[(size_t)slot * 16384 + bz * 1024 + m] = e;
    }
  }
}

// ---------------------------------------------------------------------------
// rs_inv: inv[i] = 1 / sum_{s<16} partial[s][i]
// ---------------------------------------------------------------------------
__global__ __launch_bounds__(256) void rs_inv(
    const float* __restrict__ partial, float* __restrict__ inv)
{
  const int i = blockIdx.x * 256 + threadIdx.x;
  float s = 0.f;
  #pragma unroll
  for (int p = 0; p < 16; p++) s += partial[(size_t)p * 16384 + i];
  inv[i] = 1.0f / s;
}

// ---------------------------------------------------------------------------
// pv_gemm: out = attn_masked @ v, fused softmax-apply, 2-phase dbuf.
// (unchanged — passing since R4)
// ---------------------------------------------------------------------------
__global__ __launch_bounds__(512) void pv_gemm(
    float* __restrict__ attn, const unsigned short* __restrict__ vt,
    const float* __restrict__ inv, const int* __restrict__ mask,
    float* __restrict__ out)
{
  __shared__ __align__(16) unsigned short As[2][64][40];   // 10 KB
  __shared__ __align__(16) unsigned short Bs[2][512][32];  // 64 KB

  const int tid = threadIdx.x;
  const int bz = blockIdx.z, m0 = blockIdx.x * 64;
  const int lane = tid & 63, wave = tid >> 6;
  const int n0 = wave * 64;
  const int fr = lane & 15, fq = lane >> 4;

  f32x4 acc[4][4] = {};

  const int arow = tid >> 3, acol = (tid & 7) * 4;
  float* arp = attn + ((size_t)bz * 1024 + m0 + arow) * 1024 + acol;
  const float vinv = inv[bz * 1024 + m0 + arow];
  const int* mrow = mask + bz * 1024 + acol;

  const unsigned short* gB[4];
  char* lB[4];
  #pragma unroll
  for (int r = 0; r < 4; r++) {
    const int c = r * 512 + tid;
    const int row = c >> 2;
    gB[r] = vt + ((size_t)bz * 512 + row) * 1024 + ((c & 3) ^ ((row >> 1) & 3)) * 8;
    lB[r] = (char*)&Bs[0][0][0] + c * 16;
  }

  {
    f32x4 s = *(const f32x4*)(arp);
    i32x4 mv = *(const i32x4*)(mrow);
    f32x4 p;
    p[0] = mv[0] ? __expf(s[0]) * vinv : NEG_BIG_F;
    p[1] = mv[1] ? __expf(s[1]) * vinv : NEG_BIG_F;
    p[2] = mv[2] ? __expf(s[2]) * vinv : NEG_BIG_F;
    p[3] = mv[3] ? __expf(s[3]) * vinv : NEG_BIG_F;
    *(f32x4*)(arp) = p;
    u16x4 h;
    h[0] = f2bf(p[0]); h[1] = f2bf(p[1]); h[2] = f2bf(p[2]); h[3] = f2bf(p[3]);
    *(u16x4*)&As[0][arow][acol] = h;
    #pragma unroll
    for (int r = 0; r < 4; r++) gload16(gB[r], lB[r]);
  }
  __syncthreads();

  int cur = 0;
  for (int kt = 0; kt < 1024; kt += 32) {
    const int nb = cur ^ 1;
    f32x4 s; i32x4 mv;
    const bool more = (kt + 32) < 1024;
    if (more) {
      s = *(const f32x4*)(arp + kt + 32);
      mv = *(const i32x4*)(mrow + kt + 32);
      #pragma unroll
      for (int r = 0; r < 4; r++) gload16(gB[r] + kt + 32, lB[r] + nb * 32768);
    }

    bf16x8 af[4], bv[4];
    #pragma unroll
    for (int t = 0; t < 4; t++) {
      af[t] = *(const bf16x8*)&As[cur][t * 16 + fr][fq * 8];
      const int brow = n0 + t * 16 + fr;
      bv[t] = *(const bf16x8*)&Bs[cur][brow][(fq ^ ((brow >> 1) & 3)) * 8];
    }
    #pragma unroll
    for (int mt = 0; mt < 4; mt++)
      #pragma unroll
      for (int nt = 0; nt < 4; nt++)
        acc[mt][nt] = __builtin_amdgcn_mfma_f32_16x16x32_bf16(af[mt], bv[nt], acc[mt][nt], 0, 0, 0);

    if (more) {
      f32x4 p;
      p[0] = mv[0] ? __expf(s[0]) * vinv : NEG_BIG_F;
      p[1] = mv[1] ? __expf(s[1]) * vinv : NEG_BIG_F;
      p[2] = mv[2] ? __expf(s[2]) * vinv : NEG_BIG_F;
      p[3] = mv[3] ? __expf(s[3]) * vinv : NEG_BIG_F;
      *(f32x4*)(arp + kt + 32) = p;
      u16x4 h;
      h[0] = f2bf(p[0]); h[1] = f2bf(p[1]); h[2] = f2bf(p[2]); h[3] = f2bf(p[3]);
      *(u16x4*)&As[nb][arow][acol] = h;
    }
    __syncthreads();
    cur = nb;
  }

  #pragma unroll
  for (int mt = 0; mt < 4; mt++)
    #pragma unroll
    for (int nt = 0; nt < 4; nt++)
      #pragma unroll
      for (int rr = 0; rr < 4; rr++)
        out[((size_t)bz * 1024 + m0 + mt * 16 + fq * 4 + rr) * 512 + n0 + nt * 16 + fr] =
            acc[mt][nt][rr];
}

// ---------------------------------------------------------------------------
extern "C" void kernel_launch(void* const* d_in, const int* in_sizes, int n_in,
                              void* d_out, int out_size, void* d_ws, size_t ws_size,
                              hipStream_t stream)
{
  const float* Q  = (const float*)d_in[0];
  const float* Kx = (const float*)d_in[1];
  const float* V  = (const float*)d_in[2];
  const float* WQ = (const float*)d_in[3];
  const float* WK = (const float*)d_in[4];
  const float* WV = (const float*)d_in[5];
  const int* mask = (const int*)d_in[6];

  const int B = 16, S = 1024, D = 512;
  float* out_f  = (float*)d_out;                 // B*S*D fp32
  float* attn_f = out_f + (size_t)B * S * D;     // B*S*S fp32 (scores -> attn)

  // ws: qb | kb | vt (8.39M ushorts each) | wb (0.79M) | partial | inv
  unsigned short* qb = (unsigned short*)d_ws;
  unsigned short* kb = qb + (size_t)B * S * D;
  unsigned short* vt = kb + (size_t)B * S * D;
  unsigned short* wb = vt + (size_t)B * S * D;
  float* partial = (float*)(wb + 786432);        // 16 x 16384 f32
  float* inv = partial + 262144;                 // 16384 f32

  cvtW<<<dim3(128, 1, 3), 256, 0, stream>>>(WQ, WK, WV, wb);
  projqk<<<dim3(64, 2, 2), 512, 0, stream>>>(Q, Kx, wb, qb, kb);
  projv<<<dim3(4, 4, 16), 512, 0, stream>>>(V, wb + 524288, vt);
  score256<<<dim3(4, 4, 16), 512, 0, stream>>>(qb, kb, attn_f, partial);
  rs_inv<<<dim3(64), 256, 0, stream>>>(partial, inv);
  pv_gemm<<<dim3(16, 1, 16), 512, 0, stream>>>(attn_f, vt, inv, mask, out_f);
}